// Round 1
// baseline (286.159 us; speedup 1.0000x reference)
//
#include <hip/hip_runtime.h>
#include <math.h>

// GaussianPMIModel: mean/cov over X_train (50000x32 f32), then for each eval
// point (100000x32) and each of the 496 (i<j) pairs compute
// exp(lp_diag - lp_full) for the 2x2 Gaussian; output (100000, 529) f32 with
// first 33 columns == 1.0.
//
// Closed form per pair: val = exp2(A*dxi^2 + B*dxj^2 + C*dxi*dxj + K) with
//   det = vi*vj - c^2, A = 0.5*c^2/(vi*det), B = 0.5*c^2/(vj*det),
//   C = -c/det, K = 0.5*log(det/(vi*vj)), all pre-scaled by log2(e).
//
// R4: moments chain rebuilt atomic-free. Old path funneled 206K device-scope
// float atomicAdds into 528 accumulators spanning ~33 cache lines -> per-line
// LLC serialization. New path: 128 blocks store per-block partials entry-major
// (ws[k*NB + b], plain stores, no zeroing needed), then one fused prep2 block
// reduces with coalesced float4 loads (287 KB, L2-hot) and computes coefs.
// Dispatches 4 -> 3 (zero_ws and separate prep gone). pmi_kernel untouched
// except coefficient base offset (single-variable experiment).
// Fallback to the proven atomic path if ws_size < ~300 KB.

#define D       32
#define NPAIRS  496
#define NTRAIN  50000
#define NEVAL   100000
#define OUTC    529          // 1 + 32 + 496
#define ROWS_PB 50           // eval rows per block (100000/50 = 2000 blocks)
#define MOM_CHUNK 128        // train rows per block in fallback moments kernel

#define NB      128                       // partial-sum blocks (big-ws path)
#define NTILES  ((NTRAIN + 63) / 64)      // 782 tiles of 64 rows

// Entry ids k in [0,560): k<32 = Sx col sums, 32..63 = Sxx diag, 64..559 = Sxx pairs.
// Big-ws layout (floats):
//   [0, 71680)  partials, entry-major: ws[k*NB + b]
//   CBASE_BIG = 71712: coef block (see below)
// Fallback layout: atomic sums ws[k], k in [0,560); CBASE_SMALL = 560.
// Coef block, relative to cbase: A +0, B +496, C +992, K +1488,
//   IJ (int, i|j<<8) +1984, MEAN +2480. Total 2512 floats.
#define PART_FLOATS 71680
#define CBASE_BIG   71712
#define CBASE_SMALL 560
#define COEF_FLOATS 2512

// ---------------------------------------------------------------- big-ws path

// One grid-strided pass over X_train: per-block column sums and upper-tri
// uncentered Sxx, written as plain stores (entry-major partials).
__global__ __launch_bounds__(256) void moments2_kernel(const float* __restrict__ X,
                                                       float* __restrict__ ws) {
    __shared__ float xs[64 * D];               // 8 KB tile of raw rows
    __shared__ float sdata[256];
    int t = threadIdx.x;
    int b = blockIdx.x;
    int ti = t >> 4, tj = t & 15;              // 2x2 tile: rows {2ti,2ti+1} x cols {2tj,2tj+1}
    float a00 = 0.f, a01 = 0.f, a10 = 0.f, a11 = 0.f;
    float colsum = 0.f;                        // partial sum for col (t & 31)
    const float2* xs2 = (const float2*)xs;

    for (int tile = b; tile < NTILES; tile += NB) {
        int base = tile * 64;
        for (int e = t; e < 64 * D; e += 256) { // e%32 == t%32: col invariant
            int r = e >> 5;
            int row = base + r;
            float v = (row < NTRAIN) ? X[(size_t)row * D + (e & 31)] : 0.0f;
            xs[e] = v;
            colsum += v;
        }
        __syncthreads();
        #pragma unroll 4
        for (int r = 0; r < 64; ++r) {
            float2 xi = xs2[r * 16 + ti];      // broadcast across 16 lanes
            float2 xj = xs2[r * 16 + tj];      // lane-consecutive
            a00 += xi.x * xj.x; a01 += xi.x * xj.y;
            a10 += xi.y * xj.x; a11 += xi.y * xj.y;
        }
        __syncthreads();
    }
    // reduce column sums: 8 threads share each col c = t & 31
    sdata[t] = colsum;
    __syncthreads();
    if (t < 32) {
        float tot = 0.0f;
        #pragma unroll
        for (int w = 0; w < 8; ++w) tot += sdata[t + 32 * w];
        ws[t * NB + b] = tot;                  // entry k = t
    }
    int i0 = 2 * ti, i1 = 2 * ti + 1, j0 = 2 * tj, j1 = 2 * tj + 1;
    // each (i<=j) entry emitted by exactly one thread -> plain store
    #define EMIT2(i, j, v)                                                   \
        if ((i) <= (j)) {                                                    \
            int k = ((i) == (j)) ? (32 + (i))                                \
                    : (64 + (i) * 31 - ((i) * ((i) - 1)) / 2 + ((j) - (i) - 1)); \
            ws[k * NB + b] = (v);                                            \
        }
    EMIT2(i0, j0, a00)
    EMIT2(i0, j1, a01)
    EMIT2(i1, j0, a10)
    EMIT2(i1, j1, a11)
    #undef EMIT2
}

// ------------------------------------------------------------- fallback path

__global__ void zero_ws_kernel(float* ws) {
    int t = blockIdx.x * blockDim.x + threadIdx.x;
    if (t < 560) ws[t] = 0.0f;
}

static __device__ __forceinline__ void emit_sxx(float* ws, int i, int j, float v) {
    if (i > j) return;                         // each (i<=j) entry emitted exactly once
    if (i == j) {
        atomicAdd(&ws[32 + i], v);
    } else {
        int p = i * 31 - (i * (i - 1)) / 2 + (j - i - 1);   // combinations order
        atomicAdd(&ws[64 + p], v);
    }
}

__global__ __launch_bounds__(256) void moments_kernel(const float* __restrict__ X,
                                                      float* __restrict__ ws) {
    __shared__ float xs[64 * D];
    __shared__ float sdata[256];
    int t = threadIdx.x;
    int ti = t >> 4, tj = t & 15;
    float a00 = 0.f, a01 = 0.f, a10 = 0.f, a11 = 0.f;
    float colsum = 0.f;
    int base = blockIdx.x * MOM_CHUNK;
    const float2* xs2 = (const float2*)xs;

    for (int tile = 0; tile < MOM_CHUNK; tile += 64) {
        for (int e = t; e < 64 * D; e += 256) {
            int r = e >> 5;
            int row = base + tile + r;
            float v = (row < NTRAIN) ? X[(size_t)row * D + (e & 31)] : 0.0f;
            xs[e] = v;
            colsum += v;
        }
        __syncthreads();
        #pragma unroll 4
        for (int r = 0; r < 64; ++r) {
            float2 xi = xs2[r * 16 + ti];
            float2 xj = xs2[r * 16 + tj];
            a00 += xi.x * xj.x; a01 += xi.x * xj.y;
            a10 += xi.y * xj.x; a11 += xi.y * xj.y;
        }
        __syncthreads();
    }
    sdata[t] = colsum;
    __syncthreads();
    if (t < 32) {
        float tot = 0.0f;
        #pragma unroll
        for (int w = 0; w < 8; ++w) tot += sdata[t + 32 * w];
        atomicAdd(&ws[t], tot);
    }
    int i0 = 2 * ti, i1 = 2 * ti + 1, j0 = 2 * tj, j1 = 2 * tj + 1;
    emit_sxx(ws, i0, j0, a00);
    emit_sxx(ws, i0, j1, a01);
    emit_sxx(ws, i1, j0, a10);
    emit_sxx(ws, i1, j1, a11);
}

// ------------------------------------------- shared: reduce (optional) + prep

// from_partials=1: totals[k] = sum_b ws[k*NB + b] (float4, L2-hot, coalesced).
// from_partials=0: totals[k] = ws[k] (atomic-accumulated sums).
// Then computes mean + pair coefficients at cbase layout.
__global__ __launch_bounds__(256) void prep2_kernel(float* __restrict__ ws,
                                                    int from_partials, int cbase) {
    __shared__ float totals[560];
    int t = threadIdx.x;
    if (from_partials) {
        for (int k = t; k < 560; k += 256) {
            const float4* p4 = (const float4*)(ws + (size_t)k * NB);  // 16B-aligned
            float s0 = 0.f, s1 = 0.f, s2 = 0.f, s3 = 0.f;
            #pragma unroll
            for (int q = 0; q < NB / 4; ++q) {
                float4 v = p4[q];
                s0 += v.x; s1 += v.y; s2 += v.z; s3 += v.w;
            }
            totals[k] = (s0 + s1) + (s2 + s3);
        }
    } else {
        for (int k = t; k < 560; k += 256) totals[k] = ws[k];
    }
    __syncthreads();

    const float inv_n = 1.0f / (float)NTRAIN;
    const float inv_nm1 = 1.0f / (float)(NTRAIN - 1);
    if (t < D) ws[cbase + 2480 + t] = totals[t] * inv_n;   // mean
    for (int p = t; p < NPAIRS; p += 256) {
        // map p -> (i, j), combinations(range(32), 2) order
        int i = 0, rem = p;
        while (rem >= 31 - i) { rem -= 31 - i; ++i; }
        int j = i + 1 + rem;
        float mi = totals[i] * inv_n, mj = totals[j] * inv_n;
        float vi = (totals[32 + i] - (float)NTRAIN * mi * mi) * inv_nm1;
        float vj = (totals[32 + j] - (float)NTRAIN * mj * mj) * inv_nm1;
        float c  = (totals[64 + p] - (float)NTRAIN * mi * mj) * inv_nm1;
        float det = vi * vj - c * c;
        float invdet = 1.0f / det;
        const float LOG2E = 1.44269504088896340736f;
        ws[cbase + p]        = 0.5f * c * c * invdet / vi * LOG2E;   // A (pre-scaled)
        ws[cbase + 496 + p]  = 0.5f * c * c * invdet / vj * LOG2E;   // B
        ws[cbase + 992 + p]  = -c * invdet * LOG2E;                  // C
        ws[cbase + 1488 + p] = 0.5f * logf(det / (vi * vj)) * LOG2E; // K
        ((int*)ws)[cbase + 1984 + p] = i | (j << 8);
    }
}

// ------------------------------------------------------------------ pmi eval

struct Coef { float A, B, C, K; int oi, oj; };

static __device__ __forceinline__ Coef load_coef(const float* __restrict__ ws,
                                                 int cbase, int c) {
    Coef k;
    if (c < 33) {                      // ones-column: exp2(0) == 1.0
        k.A = 0.f; k.B = 0.f; k.C = 0.f; k.K = 0.f; k.oi = 0; k.oj = 0;
    } else {
        int p = c - 33;
        k.A = ws[cbase + p];
        k.B = ws[cbase + 496 + p];
        k.C = ws[cbase + 992 + p];
        k.K = ws[cbase + 1488 + p];
        int ij = ((const int*)ws)[cbase + 1984 + p];
        k.oi = ij & 255; k.oj = ij >> 8;
    }
    return k;
}

static __device__ __forceinline__ float pair_val(const Coef& k,
                                                 const float* __restrict__ dxr) {
    float di = dxr[k.oi];              // broadcast within runs of equal i
    float dj = dxr[k.oj];              // mostly lane-consecutive -> distinct banks
    float e = fmaf(k.A, di * di, fmaf(k.B, dj * dj, fmaf(k.C, di * dj, k.K)));
    return exp2f(e);                   // coeffs pre-scaled by log2(e); exp2f -> v_exp_f32
}

__global__ __launch_bounds__(256) void pmi_kernel(const float* __restrict__ x,
                                                  const float* __restrict__ ws,
                                                  float* __restrict__ out,
                                                  int cbase) {
    __shared__ float smean[D];
    __shared__ float dx[ROWS_PB * D];
    int t = threadIdx.x;
    if (t < D) smean[t] = ws[cbase + 2480 + t];

    // Per-thread columns: t, t+256, and t+512 (only t<17). Coeffs in registers.
    Coef c0 = load_coef(ws, cbase, t);
    Coef c1 = load_coef(ws, cbase, t + 256);
    bool has3 = (t + 512) < OUTC;
    Coef c2 = load_coef(ws, cbase, has3 ? t + 512 : 33);
    __syncthreads();                   // smean ready

    int rowbase = blockIdx.x * ROWS_PB;
    const float4* x4 = (const float4*)(x + (size_t)rowbase * D);
    float4* dx4 = (float4*)dx;
    for (int f = t; f < ROWS_PB * D / 4; f += 256) {
        float4 v = x4[f];
        int cb = (f & 7) * 4;          // D/4 == 8 float4 groups per row
        v.x -= smean[cb];     v.y -= smean[cb + 1];
        v.z -= smean[cb + 2]; v.w -= smean[cb + 3];
        dx4[f] = v;
    }
    __syncthreads();

    float* orow = out + (size_t)rowbase * OUTC;
    const float* dxr = dx;
    #pragma unroll 2
    for (int r = 0; r < ROWS_PB; ++r) {
        // lanes write consecutive columns -> coalesced; plain stores so L2
        // merges adjacent waves' 256B spans into full lines (rows are 2116 B,
        // not line-aligned — nt stores caused partial-line HBM writes in R2).
        orow[t]       = pair_val(c0, dxr);
        orow[t + 256] = pair_val(c1, dxr);
        if (has3) orow[t + 512] = pair_val(c2, dxr);
        orow += OUTC; dxr += D;
    }
}

// ----------------------------------------------------------------------- host

extern "C" void kernel_launch(void* const* d_in, const int* in_sizes, int n_in,
                              void* d_out, int out_size, void* d_ws, size_t ws_size,
                              hipStream_t stream) {
    const float* X = (const float*)d_in[0];   // X_train (50000, 32) f32
    const float* x = (const float*)d_in[1];   // x       (100000, 32) f32
    float* out = (float*)d_out;               // (100000, 529) f32
    float* ws  = (float*)d_ws;

    bool big = ws_size >= (size_t)(CBASE_BIG + COEF_FLOATS + 64) * sizeof(float);
    if (big) {
        // atomic-free two-stage moments + fused prep (3 dispatches total)
        hipLaunchKernelGGL(moments2_kernel, dim3(NB), dim3(256), 0, stream, X, ws);
        hipLaunchKernelGGL(prep2_kernel, dim3(1), dim3(256), 0, stream,
                           ws, 1, CBASE_BIG);
        hipLaunchKernelGGL(pmi_kernel, dim3(NEVAL / ROWS_PB), dim3(256), 0, stream,
                           x, ws, out, CBASE_BIG);
    } else {
        // proven atomic path (4 dispatches) if workspace is tight
        hipLaunchKernelGGL(zero_ws_kernel, dim3(3), dim3(256), 0, stream, ws);
        hipLaunchKernelGGL(moments_kernel, dim3((NTRAIN + MOM_CHUNK - 1) / MOM_CHUNK),
                           dim3(256), 0, stream, X, ws);
        hipLaunchKernelGGL(prep2_kernel, dim3(1), dim3(256), 0, stream,
                           ws, 0, CBASE_SMALL);
        hipLaunchKernelGGL(pmi_kernel, dim3(NEVAL / ROWS_PB), dim3(256), 0, stream,
                           x, ws, out, CBASE_SMALL);
    }
}